// Round 12
// baseline (220.471 us; speedup 1.0000x reference)
//
#include <hip/hip_runtime.h>
#include <hip/hip_bf16.h>

typedef short v8s __attribute__((ext_vector_type(8)));
typedef short v4s __attribute__((ext_vector_type(4)));
typedef float v4f __attribute__((ext_vector_type(4)));
typedef __hip_bfloat16 bf16;

#define MFMA16x16x32(a, b, c) __builtin_amdgcn_mfma_f32_16x16x32_bf16((a), (b), (c), 0, 0, 0)

// 2^x via v_exp_f32 (HW transcendental). __exp2f doesn't exist device-side
// on this toolchain (glibc macro collision) — round-4 lesson.
__device__ __forceinline__ float exp2_hw(float x) {
  return __builtin_amdgcn_exp2f(x);
}

// Direct global->LDS DMA, 16 B per lane (dest = wave-uniform base + lane*16).
__device__ __forceinline__ void gll16(const void* g, void* l) {
  __builtin_amdgcn_global_load_lds(
      (const __attribute__((address_space(1))) void*)g,
      (__attribute__((address_space(3))) void*)l, 16, 0, 0);
}

// ---------------------------------------------------------------------------
// Weight transpose tile body: src fp32 -> dst bf16 (N=1024, K=1024) row-major.
// hl=1: src (H=16, D=1024, Dh=64), N=h*64+dh, K=d.  hl=0: src (K,N) row-major.
// ---------------------------------------------------------------------------
__device__ __forceinline__ void transpose_tile(
    const float* __restrict__ src, bf16* __restrict__ dst, int hl, int t) {
  __shared__ bf16 tile[64][65];
  int ti = t >> 4;              // K-tile
  int tj = t & 15;              // N-tile
  int lane = threadIdx.x & 63;
  int rr = threadIdx.x >> 6;
#pragma unroll
  for (int it = 0; it < 16; ++it) {
    int i = rr + it * 4;
    int gk = ti * 64 + i;
    size_t sidx = hl ? ((size_t)tj * 65536 + (size_t)gk * 64 + lane)
                     : ((size_t)gk * 1024 + tj * 64 + lane);
    tile[i][lane] = __float2bfloat16(src[sidx]);
  }
  __syncthreads();
#pragma unroll
  for (int it = 0; it < 16; ++it) {
    int j = rr + it * 4;
    dst[(size_t)(tj * 64 + j) * 1024 + ti * 64 + lane] = tile[lane][j];
  }
}

__global__ __launch_bounds__(256) void transpose_w1(
    const float* __restrict__ src, bf16* __restrict__ dst, int hl) {
  transpose_tile(src, dst, hl, blockIdx.x);
}

// ---------------------------------------------------------------------------
// prep: fused {Q,K fp32->bf16 conv} + {Wq,Wk,Wv transpose}. One launch.
// Blocks [0,4096): conv (2048 per tensor, 8 elems/thread, 16B stores).
// Blocks [4096,4864): transpose_w3 body. Branch is block-uniform.
// Round-5 lesson: d_out (16 MB) exactly fits Qb+Kb; V stays fp32 (AMODE1).
// ---------------------------------------------------------------------------
__global__ __launch_bounds__(256) void prep(
    const float* __restrict__ Q, const float* __restrict__ K,
    bf16* __restrict__ Qb, bf16* __restrict__ Kb,
    const float* __restrict__ Wq, const float* __restrict__ Wk,
    const float* __restrict__ Wv, bf16* __restrict__ WqT,
    bf16* __restrict__ WkT, bf16* __restrict__ WvT) {
  int b = blockIdx.x;
  if (b < 4096) {
    const float* src = (b < 2048) ? Q : K;
    bf16* dst = (b < 2048) ? Qb : Kb;
    size_t i = ((size_t)(b & 2047) * 256 + threadIdx.x) * 8;
    float4 a = *(const float4*)(src + i);
    float4 c = *(const float4*)(src + i + 4);
    union { v8s v; __hip_bfloat162 h[4]; } u;
    u.h[0] = __float22bfloat162_rn(make_float2(a.x, a.y));
    u.h[1] = __float22bfloat162_rn(make_float2(a.z, a.w));
    u.h[2] = __float22bfloat162_rn(make_float2(c.x, c.y));
    u.h[3] = __float22bfloat162_rn(make_float2(c.z, c.w));
    *(v8s*)(dst + i) = u.v;
  } else {
    int t = b - 4096;
    int mat = t >> 8;
    const float* src = (mat == 0) ? Wq : (mat == 1) ? Wk : Wv;
    bf16* dst = (mat == 0) ? WqT : (mat == 1) ? WkT : WvT;
    transpose_tile(src, dst, 1, t & 255);
  }
}

// ---------------------------------------------------------------------------
// gemm: tile 128xBN, BK=64, 8 waves (512 thr). BN is a template param:
// Round-10 lesson — LDS-read:MFMA ratio beats raw occupancy:
//   BN=128 (wave tile 32x64, acc[2][4], 6 reads:8 MFMA, 24 waves/CU) = 46us
//   BN=64  (wave tile 32x32, acc[2][2], 4 reads:4 MFMA, 32 waves/CU) = 52us
// -> qkv3 uses BN=128 (round-9 measured best). BN=64 is for gemm128_out,
// where the (32,y) grid at BN=128 gave only 1 block/CU (worst kernel).
// Row = 64 bf16 = 128 B -> bank-group == chunk; involution swz(r)=r&7 on
// the 8 chunks, applied to BOTH staging source and frag read (G21).
// LDS passed in (round-7 lesson: one __shared__ decl per kernel).
// AMODE 1: A fp32, converted in-register during staging. AMODE 0: bf16 gll16.
// out_mode 0: fp32 row-major + bias; 1: bf16 (B,H,S,Dh); 2: bf16 (B,H,Dh,S).
// grid (M/128, 1024/BN).
// ---------------------------------------------------------------------------
template <int AMODE, int BN>
__device__ __forceinline__ void gemm_body(
    bf16* __restrict__ As, bf16* __restrict__ Bs,
    const void* __restrict__ Ain, const bf16* __restrict__ BT,
    void* __restrict__ Cout, const float* __restrict__ bias, int out_mode) {
  const int K = 1024;
  const int J = BN / 32;        // col frags per wave (4 or 2)
  const int NB = (BN * 8) / 512;  // B staging segs per thread (2 or 1)

  int tid = threadIdx.x;                       // 0..511
  int wave = tid >> 6, lane = tid & 63, quad = lane >> 4, c16 = lane & 15;
  int rw = wave & 3, cw = wave >> 2;
  int mbase = blockIdx.x * 128, nbase = blockIdx.y * BN;

  v4f acc[2][J];
#pragma unroll
  for (int i = 0; i < 2; ++i)
#pragma unroll
    for (int j = 0; j < J; ++j) acc[i][j] = (v4f){0.f, 0.f, 0.f, 0.f};

  // A: 1024 segs (128 rows x 8 chunks) -> 2/thread; B: BN*8 segs -> NB/thr.
  // Seg s: row r=s>>3, phys chunk p=s&7; holds LOGICAL k-chunk j = p^(r&7).
  const float* a32s[2];
  const bf16* a16s[2];
#pragma unroll
  for (int ii = 0; ii < 2; ++ii) {
    int s = tid + ii * 512;
    int r = s >> 3, pch = s & 7;
    int j = pch ^ (r & 7);
    a32s[ii] = (const float*)Ain + (size_t)(mbase + r) * K + j * 8;
    a16s[ii] = (const bf16*)Ain + (size_t)(mbase + r) * K + j * 8;
  }
  const bf16* bsrc[NB];
#pragma unroll
  for (int ii = 0; ii < NB; ++ii) {
    int s = tid + ii * 512;
    int r = s >> 3, pch = s & 7;
    int j = pch ^ (r & 7);
    bsrc[ii] = BT + (size_t)(nbase + r) * K + j * 8;
  }

  int afrow = rw * 32 + c16;
  int bfrow = cw * (BN / 2) + c16;

  for (int kk = 0; kk < K; kk += 64) {
    float4 f[4];
    if (AMODE == 1) {
#pragma unroll
      for (int ii = 0; ii < 2; ++ii) {
        f[2 * ii]     = *(const float4*)(a32s[ii] + kk);
        f[2 * ii + 1] = *(const float4*)(a32s[ii] + kk + 4);
      }
    }
    __syncthreads();  // prior iteration's frag reads done
#pragma unroll
    for (int ii = 0; ii < NB; ++ii)
      gll16(bsrc[ii] + kk, &Bs[(tid + ii * 512) * 8]);
    if (AMODE == 1) {
#pragma unroll
      for (int ii = 0; ii < 2; ++ii) {
        union { v8s v; __hip_bfloat162 h[4]; } u;
        u.h[0] = __float22bfloat162_rn(make_float2(f[2 * ii].x, f[2 * ii].y));
        u.h[1] = __float22bfloat162_rn(make_float2(f[2 * ii].z, f[2 * ii].w));
        u.h[2] = __float22bfloat162_rn(
            make_float2(f[2 * ii + 1].x, f[2 * ii + 1].y));
        u.h[3] = __float22bfloat162_rn(
            make_float2(f[2 * ii + 1].z, f[2 * ii + 1].w));
        *(v8s*)&As[(tid + ii * 512) * 8] = u.v;
      }
    } else {
#pragma unroll
      for (int ii = 0; ii < 2; ++ii)
        gll16(a16s[ii] + kk, &As[(tid + ii * 512) * 8]);
    }
    __syncthreads();  // staging drained

#pragma unroll
    for (int kk2 = 0; kk2 < 2; ++kk2) {
      v8s af[2], bfr[J];
#pragma unroll
      for (int i = 0; i < 2; ++i) {
        int R = afrow + i * 16;
        af[i] = *(const v8s*)&As[R * 64 + (((kk2 * 4 + quad) ^ (R & 7)) * 8)];
      }
#pragma unroll
      for (int j = 0; j < J; ++j) {
        int R = bfrow + j * 16;
        bfr[j] = *(const v8s*)&Bs[R * 64 + (((kk2 * 4 + quad) ^ (R & 7)) * 8)];
      }
#pragma unroll
      for (int i = 0; i < 2; ++i)
#pragma unroll
        for (int j = 0; j < J; ++j)
          acc[i][j] = MFMA16x16x32(af[i], bfr[j], acc[i][j]);
    }
  }

#pragma unroll
  for (int i = 0; i < 2; ++i) {
#pragma unroll
    for (int j = 0; j < J; ++j) {
#pragma unroll
      for (int ri = 0; ri < 4; ++ri) {
        int row = mbase + rw * 32 + i * 16 + quad * 4 + ri;
        int col = nbase + cw * (BN / 2) + j * 16 + c16;
        if (out_mode == 0) {
          ((float*)Cout)[(size_t)row * 1024 + col] = acc[i][j][ri] + bias[col];
        } else {
          int b = row >> 11, s = row & 2047;
          int hh = col >> 6, dh = col & 63;
          size_t oidx = (out_mode == 1)
              ? (((size_t)b * 16 + hh) * 2048 + s) * 64 + dh
              : (((size_t)b * 16 + hh) * 64 + dh) * 2048 + s;
          ((bf16*)Cout)[oidx] = __float2bfloat16(acc[i][j][ri]);
        }
      }
    }
  }
}

// Fused QKV projection. z<2: bf16 A (pre-converted Q,K). z==2: fp32 V via
// AMODE1 in-register conversion. ONE shared As/Bs for both instantiations.
// BN=128 (round-9 measured best). grid (32,8,3) x 512 threads.
__global__ __launch_bounds__(512) void gemm128_qkv3(
    const bf16* __restrict__ Qb, const bf16* __restrict__ Kb,
    const float* __restrict__ V, const bf16* __restrict__ WqT,
    const bf16* __restrict__ WkT, const bf16* __restrict__ WvT,
    bf16* __restrict__ qh, bf16* __restrict__ kh, bf16* __restrict__ vt) {
  __shared__ __align__(16) bf16 As[128 * 64];  // 16 KB
  __shared__ __align__(16) bf16 Bs[128 * 64];  // 16 KB
  int z = blockIdx.z;
  if (z == 2) {
    gemm_body<1, 128>(As, Bs, V, WvT, vt, nullptr, 2);
  } else {
    const bf16* A = (z == 0) ? Qb : Kb;
    const bf16* BT = (z == 0) ? WqT : WkT;
    bf16* C = (z == 0) ? qh : kh;
    gemm_body<0, 128>(As, Bs, A, BT, C, nullptr, 1);
  }
}

// Single fp32-A GEMM (fallback path). BN=64. grid (M/128, 16) x 512 threads.
__global__ __launch_bounds__(512) void gemm128_f32a(
    const float* __restrict__ A, const bf16* __restrict__ BT,
    bf16* __restrict__ C, int out_mode) {
  __shared__ __align__(16) bf16 As[128 * 64];
  __shared__ __align__(16) bf16 Bs[64 * 64];
  gemm_body<1, 64>(As, Bs, A, BT, C, nullptr, out_mode);
}

// Final projection: out(fp32) = A(bf16) @ WoT^T + bias. BN=64 (2 blocks/CU
// at grid (32,16) — BN=128's 256-block grid starved the CUs).
__global__ __launch_bounds__(512) void gemm128_out(
    const bf16* __restrict__ A, const bf16* __restrict__ BT,
    const float* __restrict__ bias, float* __restrict__ C) {
  __shared__ __align__(16) bf16 As[128 * 64];
  __shared__ __align__(16) bf16 Bs[64 * 64];
  gemm_body<0, 64>(As, Bs, A, BT, C, bias, 0);
}

// ---------------------------------------------------------------------------
// flash4 v4: un-paired for occupancy. Round-10 analysis: pair-blocks gave
// 512 blocks = 2 blocks/CU x 4 waves = 8 waves/CU (2/SIMD) — lowest in the
// pipeline. Now ONE qtile per block, grid (16 h, 32 qt', 2) = 1024 blocks
// = 4 blocks/CU = 16 waves/CU. Balance without pairing: round-robin gives
// each CU qt' in {m, m+16}; the involution qtile = qt'<16 ? qt' : 47-qt'
// maps these to {m, 31-m} -> per-CU causal work sums to a constant 33
// kt-iters. (Dispatch mapping is a perf heuristic only — correctness never
// depends on it.) K/V traffic unchanged (same tile count).
// Body otherwise identical: swapped-QK^T VALU-slim softmax, hoisted masking,
// hw exp2, 1-ahead double-buffered K/V staging.
// ---------------------------------------------------------------------------
__global__ __launch_bounds__(256) void flash4(
    const bf16* __restrict__ qh, const bf16* __restrict__ kh,
    const bf16* __restrict__ vt, const int* __restrict__ pad, int b0,
    bf16* __restrict__ xb) {
  const int S = 2048;
  const float scale2 = 0.031879559795f;  // 1/sqrt(2048) * log2(e)
  const float sh2 = 4.3280851233f;       // 3 * log2(e)
  __shared__ __align__(16) bf16 Ks[2][64 * 64];
  __shared__ __align__(16) bf16 Vs[2][64 * 64];
  __shared__ __align__(16) bf16 pls[4][16][72];

  int tid = threadIdx.x;
  int wave = tid >> 6, lane = tid & 63, quad = lane >> 4, c16 = lane & 15;
  int h = blockIdx.x, qtp = blockIdx.y, bz = blockIdx.z;
  int qtile = (qtp < 16) ? qtp : 47 - qtp;  // balance involution
  int bh = bz * 16 + h;
  int kv_len = S - pad[b0 + bz];

  const bf16* kbp = kh + (size_t)bh * S * 64;
  const bf16* vbp = vt + (size_t)bh * 64 * S;

  int srow = tid >> 3;
  int sc = (tid & 7) ^ (srow & 7);
  const bf16* ks0 = kbp + (size_t)srow * 64 + sc * 8;
  const bf16* ks1 = kbp + (size_t)(srow + 32) * 64 + sc * 8;
  const bf16* vs0 = vbp + (size_t)srow * S + sc * 8;
  const bf16* vs1 = vbp + (size_t)(srow + 32) * S + sc * 8;

  const short oneb = 0x3F80;
  const v8s ones = {oneb, oneb, oneb, oneb, oneb, oneb, oneb, oneb};

  auto stage = [&](int kb, int buf) {
    gll16(ks0 + (size_t)kb * 64, &Ks[buf][tid * 8]);
    gll16(ks1 + (size_t)kb * 64, &Ks[buf][(256 + tid) * 8]);
    gll16(vs0 + kb, &Vs[buf][tid * 8]);
    gll16(vs1 + kb, &Vs[buf][(256 + tid) * 8]);
  };

  int qbase = qtile * 64;
  int r0 = qbase + wave * 16;
  int qrow = r0 + c16;
  int kmax = min(qrow, kv_len - 1);

  const bf16* qp = qh + ((size_t)bh * S + r0 + c16) * 64 + quad * 8;
  v8s qf0 = *(const v8s*)qp;
  v8s qf1 = *(const v8s*)(qp + 32);

  v4f o[4], lacc;
#pragma unroll
  for (int nt = 0; nt < 4; ++nt) o[nt] = (v4f){0.f, 0.f, 0.f, 0.f};
  lacc = (v4f){0.f, 0.f, 0.f, 0.f};

  int kend = min(qbase + 64, kv_len);
  int nkt = (kend + 63) >> 6;  // >= 1 (kv_len >= S-511)

  stage(0, 0);
  __syncthreads();

  for (int kt = 0; kt < nkt; ++kt) {
    int cur = kt & 1;
    if (kt + 1 < nkt) stage((kt + 1) * 64, cur ^ 1);
    int kb = kt * 64;

    v4f s[4];
#pragma unroll
    for (int nt = 0; nt < 4; ++nt) s[nt] = (v4f){0.f, 0.f, 0.f, 0.f};
#pragma unroll
    for (int nt = 0; nt < 4; ++nt) {
      int key = nt * 16 + c16;
      v8s k0 = *(const v8s*)&Ks[cur][key * 64 + (quad ^ (key & 7)) * 8];
      v8s k1 = *(const v8s*)&Ks[cur][key * 64 + (((quad + 4) ^ (key & 7))) * 8];
      // swapped operands: A=K (m=key), B=Q (n=qrow)
      s[nt] = MFMA16x16x32(k0, qf0, s[nt]);
      s[nt] = MFMA16x16x32(k1, qf1, s[nt]);
    }
    // lane holds keys kb + nt*16 + quad*4 + r  (r=0..3) for q-row qrow.
    bool full = (kb + 63 <= r0) && (kb + 64 <= kv_len);
    if (full) {
#pragma unroll
      for (int nt = 0; nt < 4; ++nt) {
        union { v4s v; __hip_bfloat162 h[2]; } pw;
        pw.h[0] = __float22bfloat162_rn(make_float2(
            exp2_hw(__builtin_fmaf(s[nt][0], scale2, -sh2)),
            exp2_hw(__builtin_fmaf(s[nt][1], scale2, -sh2))));
        pw.h[1] = __float22bfloat162_rn(make_float2(
            exp2_hw(__builtin_fmaf(s[nt][2], scale2, -sh2)),
            exp2_hw(__builtin_fmaf(s[nt][3], scale2, -sh2))));
        *(v4s*)&pls[wave][c16][nt * 16 + quad * 4] = pw.v;
      }
    } else {
#pragma unroll
      for (int nt = 0; nt < 4; ++nt) {
        int kp = kb + nt * 16 + quad * 4;
        float e0 = (kp + 0 <= kmax)
            ? exp2_hw(__builtin_fmaf(s[nt][0], scale2, -sh2)) : 0.f;
        float e1 = (kp + 1 <= kmax)
            ? exp2_hw(__builtin_fmaf(s[nt][1], scale2, -sh2)) : 0.f;
        float e2 = (kp + 2 <= kmax)
            ? exp2_hw(__builtin_fmaf(s[nt][2], scale2, -sh2)) : 0.f;
        float e3 = (kp + 3 <= kmax)
            ? exp2_hw(__builtin_fmaf(s[nt][3], scale2, -sh2)) : 0.f;
        union { v4s v; __hip_bfloat162 h[2]; } pw;
        pw.h[0] = __float22bfloat162_rn(make_float2(e0, e1));
        pw.h[1] = __float22bfloat162_rn(make_float2(e2, e3));
        *(v4s*)&pls[wave][c16][nt * 16 + quad * 4] = pw.v;
      }
    }
#pragma unroll
    for (int kk2 = 0; kk2 < 2; ++kk2) {
      v8s pf = *(const v8s*)&pls[wave][c16][kk2 * 32 + quad * 8];
      lacc = MFMA16x16x32(pf, ones, lacc);
#pragma unroll
      for (int nt = 0; nt < 4; ++nt) {
        int vrow = nt * 16 + c16;
        v8s vf = *(const v8s*)&Vs[cur][vrow * 64 + (((kk2 * 4 + quad) ^ (vrow & 7))) * 8];
        o[nt] = MFMA16x16x32(pf, vf, o[nt]);
      }
    }

    __syncthreads();
  }

#pragma unroll
  for (int ri = 0; ri < 4; ++ri) {
    float inv = 1.0f / lacc[ri];
    int row = r0 + quad * 4 + ri;
    size_t obase = ((size_t)bz * S + row) * 1024 + h * 64;
#pragma unroll
    for (int nt = 0; nt < 4; ++nt) {
      xb[obase + nt * 16 + c16] = __float2bfloat16(o[nt][ri] * inv);
    }
  }
}

// ---------------------------------------------------------------------------
// ws layouts (host-side branch on ws_size; constant per process => graph-safe)
// L32 (ws >= 32 MB): [0,8) qh  [8,16) kh  [16,24) vt,
//   [24,26) WqT [26,28) WkT [28,30) WvT (dead after QKV) -> [24,32) xb,
//   [0,2) WoT (overwrites dead qh after flash).
// d_out (16 MB) doubles as bf16 scratch: Qb [0,8) Kb [8,16) — exactly fits;
// dead before gemm128_out overwrites d_out with the final fp32 result.
// ---------------------------------------------------------------------------
extern "C" void kernel_launch(void* const* d_in, const int* in_sizes, int n_in,
                              void* d_out, int out_size, void* d_ws, size_t ws_size,
                              hipStream_t stream) {
  const float* Q  = (const float*)d_in[0];
  const float* K  = (const float*)d_in[1];
  const float* V  = (const float*)d_in[2];
  const int* pad  = (const int*)d_in[3];
  const float* Wq = (const float*)d_in[4];
  const float* Wk = (const float*)d_in[5];
  const float* Wv = (const float*)d_in[6];
  const float* Wo = (const float*)d_in[7];
  const float* bo = (const float*)d_in[8];
  float* out = (float*)d_out;

  char* ws = (char*)d_ws;
  const size_t MB = (size_t)1 << 20;
  const size_t SD = (size_t)2048 * 1024;
  dim3 blk(256);
  dim3 blk512(512);

  if (ws_size >= 32 * MB) {
    bf16* qh  = (bf16*)(ws + 0 * MB);
    bf16* kh  = (bf16*)(ws + 8 * MB);
    bf16* vt  = (bf16*)(ws + 16 * MB);
    bf16* WqT = (bf16*)(ws + 24 * MB);
    bf16* WkT = (bf16*)(ws + 26 * MB);
    bf16* WvT = (bf16*)(ws + 28 * MB);
    bf16* xb  = (bf16*)(ws + 24 * MB);
    bf16* woT = (bf16*)(ws + 0 * MB);
    // d_out as bf16 scratch: Qb 8 MB + Kb 8 MB = 16 MB exactly.
    bf16* Qb = (bf16*)((char*)d_out + 0 * MB);
    bf16* Kb = (bf16*)((char*)d_out + 8 * MB);

    prep<<<dim3(4864), blk, 0, stream>>>(Q, K, Qb, Kb, Wq, Wk, Wv,
                                         WqT, WkT, WvT);
    gemm128_qkv3<<<dim3(32, 8, 3), blk512, 0, stream>>>(Qb, Kb, V, WqT, WkT,
                                                        WvT, qh, kh, vt);
    flash4<<<dim3(16, 32, 2), blk, 0, stream>>>(qh, kh, vt, pad, 0, xb);
    transpose_w1<<<dim3(256), blk, 0, stream>>>(Wo, woT, 0);
    gemm128_out<<<dim3(32, 16), blk512, 0, stream>>>(xb, woT, bo, out);
  } else {
    // 16 MB per-batch fallback (proven AMODE1 path)
    bf16* qh    = (bf16*)(ws + 0 * MB);
    bf16* kh    = (bf16*)(ws + 4 * MB);
    bf16* vt    = (bf16*)(ws + 8 * MB);
    bf16* wslot = (bf16*)(ws + 12 * MB);
    bf16* xb    = (bf16*)(ws + 12 * MB);
    bf16* woT   = (bf16*)(ws + 0 * MB);
    for (int b = 0; b < 2; ++b) {
      const float* Qb = Q + (size_t)b * SD;
      const float* Kb = K + (size_t)b * SD;
      const float* Vb = V + (size_t)b * SD;
      float* outb = out + (size_t)b * SD;
      transpose_w1<<<dim3(256), blk, 0, stream>>>(Wv, wslot, 1);
      gemm128_f32a<<<dim3(16, 16), blk512, 0, stream>>>(Vb, wslot, vt, 2);
      transpose_w1<<<dim3(256), blk, 0, stream>>>(Wq, wslot, 1);
      gemm128_f32a<<<dim3(16, 16), blk512, 0, stream>>>(Qb, wslot, qh, 1);
      transpose_w1<<<dim3(256), blk, 0, stream>>>(Wk, wslot, 1);
      gemm128_f32a<<<dim3(16, 16), blk512, 0, stream>>>(Kb, wslot, kh, 1);
      flash4<<<dim3(16, 32, 1), blk, 0, stream>>>(qh, kh, vt, pad, b, xb);
      transpose_w1<<<dim3(256), blk, 0, stream>>>(Wo, woT, 0);
      gemm128_out<<<dim3(16, 16), blk512, 0, stream>>>(xb, woT, bo, outb);
    }
  }
}

// Round 13
// 213.185 us; speedup vs baseline: 1.0342x; 1.0342x over previous
//
#include <hip/hip_runtime.h>
#include <hip/hip_bf16.h>

typedef short v8s __attribute__((ext_vector_type(8)));
typedef short v4s __attribute__((ext_vector_type(4)));
typedef float v4f __attribute__((ext_vector_type(4)));
typedef __hip_bfloat16 bf16;

#define MFMA16x16x32(a, b, c) __builtin_amdgcn_mfma_f32_16x16x32_bf16((a), (b), (c), 0, 0, 0)

// 2^x via v_exp_f32 (HW transcendental). __exp2f doesn't exist device-side
// on this toolchain (glibc macro collision) — round-4 lesson.
__device__ __forceinline__ float exp2_hw(float x) {
  return __builtin_amdgcn_exp2f(x);
}

// Direct global->LDS DMA, 16 B per lane (dest = wave-uniform base + lane*16).
__device__ __forceinline__ void gll16(const void* g, void* l) {
  __builtin_amdgcn_global_load_lds(
      (const __attribute__((address_space(1))) void*)g,
      (__attribute__((address_space(3))) void*)l, 16, 0, 0);
}

// ---------------------------------------------------------------------------
// Weight transpose tile body: src fp32 -> dst bf16 (N=1024, K=1024) row-major.
// hl=1: src (H=16, D=1024, Dh=64), N=h*64+dh, K=d.  hl=0: src (K,N) row-major.
// ---------------------------------------------------------------------------
__device__ __forceinline__ void transpose_tile(
    const float* __restrict__ src, bf16* __restrict__ dst, int hl, int t) {
  __shared__ bf16 tile[64][65];
  int ti = t >> 4;              // K-tile
  int tj = t & 15;              // N-tile
  int lane = threadIdx.x & 63;
  int rr = threadIdx.x >> 6;
#pragma unroll
  for (int it = 0; it < 16; ++it) {
    int i = rr + it * 4;
    int gk = ti * 64 + i;
    size_t sidx = hl ? ((size_t)tj * 65536 + (size_t)gk * 64 + lane)
                     : ((size_t)gk * 1024 + tj * 64 + lane);
    tile[i][lane] = __float2bfloat16(src[sidx]);
  }
  __syncthreads();
#pragma unroll
  for (int it = 0; it < 16; ++it) {
    int j = rr + it * 4;
    dst[(size_t)(tj * 64 + j) * 1024 + ti * 64 + lane] = tile[lane][j];
  }
}

__global__ __launch_bounds__(256) void transpose_w1(
    const float* __restrict__ src, bf16* __restrict__ dst, int hl) {
  transpose_tile(src, dst, hl, blockIdx.x);
}

// ---------------------------------------------------------------------------
// prep: fused {Q,K fp32->bf16 conv} + {Wq,Wk,Wv transpose}. One launch.
// Blocks [0,4096): conv (2048 per tensor, 8 elems/thread, 16B stores).
// Blocks [4096,4864): transpose_w3 body. Branch is block-uniform.
// Round-5 lesson: d_out (16 MB) exactly fits Qb+Kb; V stays fp32 (AMODE1).
// ---------------------------------------------------------------------------
__global__ __launch_bounds__(256) void prep(
    const float* __restrict__ Q, const float* __restrict__ K,
    bf16* __restrict__ Qb, bf16* __restrict__ Kb,
    const float* __restrict__ Wq, const float* __restrict__ Wk,
    const float* __restrict__ Wv, bf16* __restrict__ WqT,
    bf16* __restrict__ WkT, bf16* __restrict__ WvT) {
  int b = blockIdx.x;
  if (b < 4096) {
    const float* src = (b < 2048) ? Q : K;
    bf16* dst = (b < 2048) ? Qb : Kb;
    size_t i = ((size_t)(b & 2047) * 256 + threadIdx.x) * 8;
    float4 a = *(const float4*)(src + i);
    float4 c = *(const float4*)(src + i + 4);
    union { v8s v; __hip_bfloat162 h[4]; } u;
    u.h[0] = __float22bfloat162_rn(make_float2(a.x, a.y));
    u.h[1] = __float22bfloat162_rn(make_float2(a.z, a.w));
    u.h[2] = __float22bfloat162_rn(make_float2(c.x, c.y));
    u.h[3] = __float22bfloat162_rn(make_float2(c.z, c.w));
    *(v8s*)(dst + i) = u.v;
  } else {
    int t = b - 4096;
    int mat = t >> 8;
    const float* src = (mat == 0) ? Wq : (mat == 1) ? Wk : Wv;
    bf16* dst = (mat == 0) ? WqT : (mat == 1) ? WkT : WvT;
    transpose_tile(src, dst, 1, t & 255);
  }
}

// ---------------------------------------------------------------------------
// gemm: tile 128xBN, BK=64, 8 waves (512 thr). BN is a template param:
// Round-10/12 lessons — LDS-read:MFMA ratio beats raw occupancy:
//   BN=128 (wave tile 32x64, acc[2][4], 24 waves/CU) ~ 46-50us (qkv best)
//   BN=64  (wave tile 32x32, acc[2][2], 32 waves/CU) ~ 52us
// -> qkv3 uses BN=128. BN=64 is for gemm128_out, where the (32,y) grid at
// BN=128 gave only 1 block/CU (worst kernel).
// Row = 64 bf16 = 128 B -> bank-group == chunk; involution swz(r)=r&7 on
// the 8 chunks, applied to BOTH staging source and frag read (G21).
// LDS passed in (round-7 lesson: one __shared__ decl per kernel).
// AMODE 1: A fp32, converted in-register during staging. AMODE 0: bf16 gll16.
// out_mode 0: fp32 row-major + bias; 1: bf16 (B,H,S,Dh); 2: bf16 (B,H,Dh,S).
// grid (M/128, 1024/BN).
// ---------------------------------------------------------------------------
template <int AMODE, int BN>
__device__ __forceinline__ void gemm_body(
    bf16* __restrict__ As, bf16* __restrict__ Bs,
    const void* __restrict__ Ain, const bf16* __restrict__ BT,
    void* __restrict__ Cout, const float* __restrict__ bias, int out_mode) {
  const int K = 1024;
  const int J = BN / 32;        // col frags per wave (4 or 2)
  const int NB = (BN * 8) / 512;  // B staging segs per thread (2 or 1)

  int tid = threadIdx.x;                       // 0..511
  int wave = tid >> 6, lane = tid & 63, quad = lane >> 4, c16 = lane & 15;
  int rw = wave & 3, cw = wave >> 2;
  int mbase = blockIdx.x * 128, nbase = blockIdx.y * BN;

  v4f acc[2][J];
#pragma unroll
  for (int i = 0; i < 2; ++i)
#pragma unroll
    for (int j = 0; j < J; ++j) acc[i][j] = (v4f){0.f, 0.f, 0.f, 0.f};

  // A: 1024 segs (128 rows x 8 chunks) -> 2/thread; B: BN*8 segs -> NB/thr.
  // Seg s: row r=s>>3, phys chunk p=s&7; holds LOGICAL k-chunk j = p^(r&7).
  const float* a32s[2];
  const bf16* a16s[2];
#pragma unroll
  for (int ii = 0; ii < 2; ++ii) {
    int s = tid + ii * 512;
    int r = s >> 3, pch = s & 7;
    int j = pch ^ (r & 7);
    a32s[ii] = (const float*)Ain + (size_t)(mbase + r) * K + j * 8;
    a16s[ii] = (const bf16*)Ain + (size_t)(mbase + r) * K + j * 8;
  }
  const bf16* bsrc[NB];
#pragma unroll
  for (int ii = 0; ii < NB; ++ii) {
    int s = tid + ii * 512;
    int r = s >> 3, pch = s & 7;
    int j = pch ^ (r & 7);
    bsrc[ii] = BT + (size_t)(nbase + r) * K + j * 8;
  }

  int afrow = rw * 32 + c16;
  int bfrow = cw * (BN / 2) + c16;

  for (int kk = 0; kk < K; kk += 64) {
    float4 f[4];
    if (AMODE == 1) {
#pragma unroll
      for (int ii = 0; ii < 2; ++ii) {
        f[2 * ii]     = *(const float4*)(a32s[ii] + kk);
        f[2 * ii + 1] = *(const float4*)(a32s[ii] + kk + 4);
      }
    }
    __syncthreads();  // prior iteration's frag reads done
#pragma unroll
    for (int ii = 0; ii < NB; ++ii)
      gll16(bsrc[ii] + kk, &Bs[(tid + ii * 512) * 8]);
    if (AMODE == 1) {
#pragma unroll
      for (int ii = 0; ii < 2; ++ii) {
        union { v8s v; __hip_bfloat162 h[4]; } u;
        u.h[0] = __float22bfloat162_rn(make_float2(f[2 * ii].x, f[2 * ii].y));
        u.h[1] = __float22bfloat162_rn(make_float2(f[2 * ii].z, f[2 * ii].w));
        u.h[2] = __float22bfloat162_rn(
            make_float2(f[2 * ii + 1].x, f[2 * ii + 1].y));
        u.h[3] = __float22bfloat162_rn(
            make_float2(f[2 * ii + 1].z, f[2 * ii + 1].w));
        *(v8s*)&As[(tid + ii * 512) * 8] = u.v;
      }
    } else {
#pragma unroll
      for (int ii = 0; ii < 2; ++ii)
        gll16(a16s[ii] + kk, &As[(tid + ii * 512) * 8]);
    }
    __syncthreads();  // staging drained

#pragma unroll
    for (int kk2 = 0; kk2 < 2; ++kk2) {
      v8s af[2], bfr[J];
#pragma unroll
      for (int i = 0; i < 2; ++i) {
        int R = afrow + i * 16;
        af[i] = *(const v8s*)&As[R * 64 + (((kk2 * 4 + quad) ^ (R & 7)) * 8)];
      }
#pragma unroll
      for (int j = 0; j < J; ++j) {
        int R = bfrow + j * 16;
        bfr[j] = *(const v8s*)&Bs[R * 64 + (((kk2 * 4 + quad) ^ (R & 7)) * 8)];
      }
#pragma unroll
      for (int i = 0; i < 2; ++i)
#pragma unroll
        for (int j = 0; j < J; ++j)
          acc[i][j] = MFMA16x16x32(af[i], bfr[j], acc[i][j]);
    }
  }

#pragma unroll
  for (int i = 0; i < 2; ++i) {
#pragma unroll
    for (int j = 0; j < J; ++j) {
#pragma unroll
      for (int ri = 0; ri < 4; ++ri) {
        int row = mbase + rw * 32 + i * 16 + quad * 4 + ri;
        int col = nbase + cw * (BN / 2) + j * 16 + c16;
        if (out_mode == 0) {
          ((float*)Cout)[(size_t)row * 1024 + col] = acc[i][j][ri] + bias[col];
        } else {
          int b = row >> 11, s = row & 2047;
          int hh = col >> 6, dh = col & 63;
          size_t oidx = (out_mode == 1)
              ? (((size_t)b * 16 + hh) * 2048 + s) * 64 + dh
              : (((size_t)b * 16 + hh) * 64 + dh) * 2048 + s;
          ((bf16*)Cout)[oidx] = __float2bfloat16(acc[i][j][ri]);
        }
      }
    }
  }
}

// Fused QKV projection. z<2: bf16 A (pre-converted Q,K). z==2: fp32 V via
// AMODE1 in-register conversion. ONE shared As/Bs for both instantiations.
// BN=128. grid (32,8,3) x 512 threads.
__global__ __launch_bounds__(512) void gemm128_qkv3(
    const bf16* __restrict__ Qb, const bf16* __restrict__ Kb,
    const float* __restrict__ V, const bf16* __restrict__ WqT,
    const bf16* __restrict__ WkT, const bf16* __restrict__ WvT,
    bf16* __restrict__ qh, bf16* __restrict__ kh, bf16* __restrict__ vt) {
  __shared__ __align__(16) bf16 As[128 * 64];  // 16 KB
  __shared__ __align__(16) bf16 Bs[128 * 64];  // 16 KB
  int z = blockIdx.z;
  if (z == 2) {
    gemm_body<1, 128>(As, Bs, V, WvT, vt, nullptr, 2);
  } else {
    const bf16* A = (z == 0) ? Qb : Kb;
    const bf16* BT = (z == 0) ? WqT : WkT;
    bf16* C = (z == 0) ? qh : kh;
    gemm_body<0, 128>(As, Bs, A, BT, C, nullptr, 1);
  }
}

// Single fp32-A GEMM (fallback path). BN=64. grid (M/128, 16) x 512 threads.
__global__ __launch_bounds__(512) void gemm128_f32a(
    const float* __restrict__ A, const bf16* __restrict__ BT,
    bf16* __restrict__ C, int out_mode) {
  __shared__ __align__(16) bf16 As[128 * 64];
  __shared__ __align__(16) bf16 Bs[64 * 64];
  gemm_body<1, 64>(As, Bs, A, BT, C, nullptr, out_mode);
}

// Final projection: out(fp32) = A(bf16) @ WoT^T + bias. BN=64 (2 blocks/CU
// at grid (32,16) — BN=128's 256-block grid starved the CUs).
__global__ __launch_bounds__(512) void gemm128_out(
    const bf16* __restrict__ A, const bf16* __restrict__ BT,
    const float* __restrict__ bias, float* __restrict__ C) {
  __shared__ __align__(16) bf16 As[128 * 64];
  __shared__ __align__(16) bf16 Bs[64 * 64];
  gemm_body<0, 64>(As, Bs, A, BT, C, bias, 0);
}

// ---------------------------------------------------------------------------
// flash4 v5: SHARED-PAIR 8-wave block (512 thr). Round-12 lesson: dispatch-
// order balancing regressed; balance must be by construction. One block owns
// the pair (A = 31-pr long, B = pr short) CONCURRENTLY: waves 0-3 -> A,
// waves 4-7 -> B. K/V tiles staged ONCE for both (B's kt range is a prefix
// of A's) -> ~26% less K/V staging traffic; block duration = nktA (max, not
// sum); 16 waves/CU resident (vs 8 in the paired-sequential version).
// Per-CU duration balance: pr = bz ? 15-qtp : qtp, so round-robin dispatch
// gives a CU one (32-pr)-iter and one (17+pr)-iter block = constant 49
// (heuristic only — correctness never depends on dispatch mapping).
// Short waves idle past myNkt but hit every barrier (compute guarded by
// kt < myNkt; stage+barriers unconditional -> no divergent-barrier hazard).
// LDS 50 KB: Ks 16 + Vs 16 + pls[8] 18. Body per-wave identical to v3:
// swapped-QK^T VALU-slim softmax, hoisted masking, hw exp2, 1-ahead dbuf.
// grid (16 h, 16 qtp, nb) x 512.
// ---------------------------------------------------------------------------
__global__ __launch_bounds__(512) void flash4(
    const bf16* __restrict__ qh, const bf16* __restrict__ kh,
    const bf16* __restrict__ vt, const int* __restrict__ pad, int b0,
    bf16* __restrict__ xb) {
  const int S = 2048;
  const float scale2 = 0.031879559795f;  // 1/sqrt(2048) * log2(e)
  const float sh2 = 4.3280851233f;       // 3 * log2(e)
  __shared__ __align__(16) bf16 Ks[2][64 * 64];   // 16 KB
  __shared__ __align__(16) bf16 Vs[2][64 * 64];   // 16 KB
  __shared__ __align__(16) bf16 pls[8][16][72];   // 18 KB

  int tid = threadIdx.x;                  // 0..511
  int wave = tid >> 6, lane = tid & 63, quad = lane >> 4, c16 = lane & 15;
  int wq = wave >> 2, wl = wave & 3;      // wq: 0 = long tile A, 1 = short B
  int h = blockIdx.x, qtp = blockIdx.y, bz = blockIdx.z;
  int pr = bz ? (15 - qtp) : qtp;         // per-CU duration balance
  int qtile = wq ? pr : (31 - pr);
  int bh = bz * 16 + h;
  int kv_len = S - pad[b0 + bz];

  const bf16* kbp = kh + (size_t)bh * S * 64;
  const bf16* vbp = vt + (size_t)bh * 64 * S;

  // staging: 512 threads cover 64 rows x 8 chunks for K and V each (1 gll16
  // apiece); XOR source swizzle, dest lane-linear (G21).
  int srow = tid >> 3;                    // 0..63
  int sc = (tid & 7) ^ (srow & 7);
  const bf16* ksrc = kbp + (size_t)srow * 64 + sc * 8;
  const bf16* vsrc = vbp + (size_t)srow * S + sc * 8;

  const short oneb = 0x3F80;
  const v8s ones = {oneb, oneb, oneb, oneb, oneb, oneb, oneb, oneb};

  auto stage = [&](int kb, int buf) {
    gll16(ksrc + (size_t)kb * 64, &Ks[buf][tid * 8]);
    gll16(vsrc + kb, &Vs[buf][tid * 8]);
  };

  int qbase = qtile * 64;
  int r0 = qbase + wl * 16;
  int qrow = r0 + c16;
  int kmax = min(qrow, kv_len - 1);

  const bf16* qp = qh + ((size_t)bh * S + r0 + c16) * 64 + quad * 8;
  v8s qf0 = *(const v8s*)qp;
  v8s qf1 = *(const v8s*)(qp + 32);

  v4f o[4], lacc;
#pragma unroll
  for (int nt = 0; nt < 4; ++nt) o[nt] = (v4f){0.f, 0.f, 0.f, 0.f};
  lacc = (v4f){0.f, 0.f, 0.f, 0.f};

  // Block-uniform loop bound = long tile's count; per-wave compute count.
  int kendA = min((31 - pr) * 64 + 64, kv_len);
  int nktA = (kendA + 63) >> 6;
  int kend = min(qbase + 64, kv_len);
  int myNkt = (kend + 63) >> 6;          // <= nktA always (qtileB < qtileA)

  stage(0, 0);
  __syncthreads();

  for (int kt = 0; kt < nktA; ++kt) {
    int cur = kt & 1;
    if (kt + 1 < nktA) stage((kt + 1) * 64, cur ^ 1);
    if (kt < myNkt) {
      int kb = kt * 64;
      v4f s[4];
#pragma unroll
      for (int nt = 0; nt < 4; ++nt) s[nt] = (v4f){0.f, 0.f, 0.f, 0.f};
#pragma unroll
      for (int nt = 0; nt < 4; ++nt) {
        int key = nt * 16 + c16;
        v8s k0 = *(const v8s*)&Ks[cur][key * 64 + (quad ^ (key & 7)) * 8];
        v8s k1 = *(const v8s*)&Ks[cur][key * 64 + (((quad + 4) ^ (key & 7))) * 8];
        // swapped operands: A=K (m=key), B=Q (n=qrow)
        s[nt] = MFMA16x16x32(k0, qf0, s[nt]);
        s[nt] = MFMA16x16x32(k1, qf1, s[nt]);
      }
      // lane holds keys kb + nt*16 + quad*4 + r (r=0..3) for q-row qrow.
      bool full = (kb + 63 <= r0) && (kb + 64 <= kv_len);
      if (full) {
#pragma unroll
        for (int nt = 0; nt < 4; ++nt) {
          union { v4s v; __hip_bfloat162 h[2]; } pw;
          pw.h[0] = __float22bfloat162_rn(make_float2(
              exp2_hw(__builtin_fmaf(s[nt][0], scale2, -sh2)),
              exp2_hw(__builtin_fmaf(s[nt][1], scale2, -sh2))));
          pw.h[1] = __float22bfloat162_rn(make_float2(
              exp2_hw(__builtin_fmaf(s[nt][2], scale2, -sh2)),
              exp2_hw(__builtin_fmaf(s[nt][3], scale2, -sh2))));
          *(v4s*)&pls[wave][c16][nt * 16 + quad * 4] = pw.v;
        }
      } else {
#pragma unroll
        for (int nt = 0; nt < 4; ++nt) {
          int kp = kb + nt * 16 + quad * 4;
          float e0 = (kp + 0 <= kmax)
              ? exp2_hw(__builtin_fmaf(s[nt][0], scale2, -sh2)) : 0.f;
          float e1 = (kp + 1 <= kmax)
              ? exp2_hw(__builtin_fmaf(s[nt][1], scale2, -sh2)) : 0.f;
          float e2 = (kp + 2 <= kmax)
              ? exp2_hw(__builtin_fmaf(s[nt][2], scale2, -sh2)) : 0.f;
          float e3 = (kp + 3 <= kmax)
              ? exp2_hw(__builtin_fmaf(s[nt][3], scale2, -sh2)) : 0.f;
          union { v4s v; __hip_bfloat162 h[2]; } pw;
          pw.h[0] = __float22bfloat162_rn(make_float2(e0, e1));
          pw.h[1] = __float22bfloat162_rn(make_float2(e2, e3));
          *(v4s*)&pls[wave][c16][nt * 16 + quad * 4] = pw.v;
        }
      }
#pragma unroll
      for (int kk2 = 0; kk2 < 2; ++kk2) {
        v8s pf = *(const v8s*)&pls[wave][c16][kk2 * 32 + quad * 8];
        lacc = MFMA16x16x32(pf, ones, lacc);
#pragma unroll
        for (int nt = 0; nt < 4; ++nt) {
          int vrow = nt * 16 + c16;
          v8s vf = *(const v8s*)&Vs[cur][vrow * 64 + (((kk2 * 4 + quad) ^ (vrow & 7))) * 8];
          o[nt] = MFMA16x16x32(pf, vf, o[nt]);
        }
      }
    }
    __syncthreads();
  }

#pragma unroll
  for (int ri = 0; ri < 4; ++ri) {
    float inv = 1.0f / lacc[ri];
    int row = r0 + quad * 4 + ri;
    size_t obase = ((size_t)bz * S + row) * 1024 + h * 64;
#pragma unroll
    for (int nt = 0; nt < 4; ++nt) {
      xb[obase + nt * 16 + c16] = __float2bfloat16(o[nt][ri] * inv);
    }
  }
}

// ---------------------------------------------------------------------------
// ws layouts (host-side branch on ws_size; constant per process => graph-safe)
// L32 (ws >= 32 MB): [0,8) qh  [8,16) kh  [16,24) vt,
//   [24,26) WqT [26,28) WkT [28,30) WvT (dead after QKV) -> [24,32) xb,
//   [0,2) WoT (overwrites dead qh after flash).
// d_out (16 MB) doubles as bf16 scratch: Qb [0,8) Kb [8,16) — exactly fits;
// dead before gemm128_out overwrites d_out with the final fp32 result.
// ---------------------------------------------------------------------------
extern "C" void kernel_launch(void* const* d_in, const int* in_sizes, int n_in,
                              void* d_out, int out_size, void* d_ws, size_t ws_size,
                              hipStream_t stream) {
  const float* Q  = (const float*)d_in[0];
  const float* K  = (const float*)d_in[1];
  const float* V  = (const float*)d_in[2];
  const int* pad  = (const int*)d_in[3];
  const float* Wq = (const float*)d_in[4];
  const float* Wk = (const float*)d_in[5];
  const float* Wv = (const float*)d_in[6];
  const float* Wo = (const float*)d_in[7];
  const float* bo = (const float*)d_in[8];
  float* out = (float*)d_out;

  char* ws = (char*)d_ws;
  const size_t MB = (size_t)1 << 20;
  const size_t SD = (size_t)2048 * 1024;
  dim3 blk(256);
  dim3 blk512(512);

  if (ws_size >= 32 * MB) {
    bf16* qh  = (bf16*)(ws + 0 * MB);
    bf16* kh  = (bf16*)(ws + 8 * MB);
    bf16* vt  = (bf16*)(ws + 16 * MB);
    bf16* WqT = (bf16*)(ws + 24 * MB);
    bf16* WkT = (bf16*)(ws + 26 * MB);
    bf16* WvT = (bf16*)(ws + 28 * MB);
    bf16* xb  = (bf16*)(ws + 24 * MB);
    bf16* woT = (bf16*)(ws + 0 * MB);
    // d_out as bf16 scratch: Qb 8 MB + Kb 8 MB = 16 MB exactly.
    bf16* Qb = (bf16*)((char*)d_out + 0 * MB);
    bf16* Kb = (bf16*)((char*)d_out + 8 * MB);

    prep<<<dim3(4864), blk, 0, stream>>>(Q, K, Qb, Kb, Wq, Wk, Wv,
                                         WqT, WkT, WvT);
    gemm128_qkv3<<<dim3(32, 8, 3), blk512, 0, stream>>>(Qb, Kb, V, WqT, WkT,
                                                        WvT, qh, kh, vt);
    flash4<<<dim3(16, 16, 2), blk512, 0, stream>>>(qh, kh, vt, pad, 0, xb);
    transpose_w1<<<dim3(256), blk, 0, stream>>>(Wo, woT, 0);
    gemm128_out<<<dim3(32, 16), blk512, 0, stream>>>(xb, woT, bo, out);
  } else {
    // 16 MB per-batch fallback (proven AMODE1 path)
    bf16* qh    = (bf16*)(ws + 0 * MB);
    bf16* kh    = (bf16*)(ws + 4 * MB);
    bf16* vt    = (bf16*)(ws + 8 * MB);
    bf16* wslot = (bf16*)(ws + 12 * MB);
    bf16* xb    = (bf16*)(ws + 12 * MB);
    bf16* woT   = (bf16*)(ws + 0 * MB);
    for (int b = 0; b < 2; ++b) {
      const float* Qb = Q + (size_t)b * SD;
      const float* Kb = K + (size_t)b * SD;
      const float* Vb = V + (size_t)b * SD;
      float* outb = out + (size_t)b * SD;
      transpose_w1<<<dim3(256), blk, 0, stream>>>(Wv, wslot, 1);
      gemm128_f32a<<<dim3(16, 16), blk512, 0, stream>>>(Vb, wslot, vt, 2);
      transpose_w1<<<dim3(256), blk, 0, stream>>>(Wq, wslot, 1);
      gemm128_f32a<<<dim3(16, 16), blk512, 0, stream>>>(Qb, wslot, qh, 1);
      transpose_w1<<<dim3(256), blk, 0, stream>>>(Wk, wslot, 1);
      gemm128_f32a<<<dim3(16, 16), blk512, 0, stream>>>(Kb, wslot, kh, 1);
      flash4<<<dim3(16, 16, 1), blk512, 0, stream>>>(qh, kh, vt, pad, b, xb);
      transpose_w1<<<dim3(256), blk, 0, stream>>>(Wo, woT, 0);
      gemm128_out<<<dim3(16, 16), blk512, 0, stream>>>(xb, woT, bo, outb);
    }
  }
}